// Round 1
// baseline (684.828 us; speedup 1.0000x reference)
//
#include <hip/hip_runtime.h>
#include <math.h>

#define TPB 256

// ---------------- CSR build ----------------

__global__ void k_init(float* deg, int* cnt, int n) {
    int i = blockIdx.x * blockDim.x + threadIdx.x;
    if (i < n) { deg[i] = 1.0f; cnt[i] = 0; }   // self-loop weight 1 pre-added
}

__global__ void k_count(const int* __restrict__ ei, const float* __restrict__ ew,
                        float* deg, int* cnt, int E) {
    int e = blockIdx.x * blockDim.x + threadIdx.x;
    if (e < E) {
        int d = ei[E + e];                       // dst row of edge_index
        atomicAdd(&deg[d], ew[e]);
        atomicAdd(&cnt[d], 1);
    }
}

__global__ void k_rsqrt(float* deg, int n) {
    int i = blockIdx.x * blockDim.x + threadIdx.x;
    if (i < n) { float d = deg[i]; deg[i] = d > 0.f ? rsqrtf(d) : 0.f; }
}

// exclusive scan of cnt[] -> row_start[], tile size 1024 (256 thr x 4)
__global__ void k_scan1(const int* __restrict__ cnt, int* __restrict__ excl,
                        int* __restrict__ tileSums, int n) {
    __shared__ int sh[256];
    int tid = threadIdx.x;
    int base = blockIdx.x * 1024;
    int idx0 = base + tid * 4;
    int v[4]; int tot = 0;
#pragma unroll
    for (int j = 0; j < 4; j++) { int i = idx0 + j; v[j] = (i < n) ? cnt[i] : 0; tot += v[j]; }
    sh[tid] = tot;
    __syncthreads();
    for (int off = 1; off < 256; off <<= 1) {
        int t = (tid >= off) ? sh[tid - off] : 0;
        __syncthreads();
        sh[tid] += t;
        __syncthreads();
    }
    int incl = sh[tid];
    if (tid == 255) tileSums[blockIdx.x] = incl;
    int run = incl - tot;                        // exclusive prefix for this thread
#pragma unroll
    for (int j = 0; j < 4; j++) { int i = idx0 + j; if (i < n) excl[i] = run; run += v[j]; }
}

__global__ void k_scan2(int* tileSums, int nTiles) {
    if (threadIdx.x == 0 && blockIdx.x == 0) {
        int acc = 0;
        for (int t = 0; t < nTiles; t++) { int v = tileSums[t]; tileSums[t] = acc; acc += v; }
    }
}

__global__ void k_scan3(int* __restrict__ excl, const int* __restrict__ tileSums,
                        int* __restrict__ fill, int n, int total) {
    int i = blockIdx.x * blockDim.x + threadIdx.x;
    if (i < n) { excl[i] += tileSums[i >> 10]; fill[i] = 0; }
    if (i == 0) excl[n] = total;
}

__global__ void k_scatter(const int* __restrict__ ei, const float* __restrict__ ew,
                          const float* __restrict__ dinv, const int* __restrict__ row_start,
                          int* fill, int2* __restrict__ csr, int E) {
    int e = blockIdx.x * blockDim.x + threadIdx.x;
    if (e >= E) return;
    int s = ei[e], d = ei[E + e];
    int r = atomicAdd(&fill[d], 1);
    float w = ew[e] * dinv[s] * dinv[d];         // full sym-norm weight
    int2 v; v.x = s; v.y = __float_as_int(w);
    csr[row_start[d] + r] = v;
}

// ---------------- per-layer compute ----------------

// XW[n, 0:96] = x[n,:] @ [W_I | W_T | W_O]  (conv indices 0,4,6; F-gate is dead: C_old=0)
__global__ __launch_bounds__(256) void k_gemm(const float* __restrict__ x,
                                              const float* __restrict__ cw,
                                              float* __restrict__ XW, int N, int l) {
    __shared__ float Ws[32][96];
    __shared__ float Xs[32][33];
    int tid = threadIdx.x;
    for (int i = tid; i < 3072; i += 256) {
        int k = i / 96, c = i - k * 96;
        int g = c >> 5, o = c & 31;
        int j = (g == 0) ? 0 : ((g == 1) ? 4 : 6);
        Ws[k][c] = cw[(((l * 8 + j) * 32) + k) * 32 + o];
    }
    int row0 = blockIdx.x * 32;
    for (int i = tid; i < 1024; i += 256) {
        int r = i >> 5, k = i & 31; int gr = row0 + r;
        Xs[r][k] = (gr < N) ? x[(size_t)gr * 32 + k] : 0.f;
    }
    __syncthreads();
    int r = tid >> 3, g8 = tid & 7;
    float acc[12];
#pragma unroll
    for (int j = 0; j < 12; j++) acc[j] = 0.f;
#pragma unroll
    for (int k = 0; k < 32; k++) {
        float xv = Xs[r][k];
#pragma unroll
        for (int j = 0; j < 12; j++) acc[j] += xv * Ws[k][g8 * 12 + j];
    }
    int gr = row0 + r;
    if (gr < N) {
        float* o = XW + (size_t)gr * 96 + g8 * 12;
#pragma unroll
        for (int j = 0; j < 12; j++) o[j] = acc[j];
    }
}

// one wave per node: gather sum over in-edges of nw*XW[src], fused gate math
__global__ __launch_bounds__(256) void k_gather(const float* __restrict__ XW,
                                                const int* __restrict__ row_start,
                                                const int2* __restrict__ csr,
                                                const float* __restrict__ dinv,
                                                const float* __restrict__ cb,
                                                const float* __restrict__ bgp,
                                                const float* __restrict__ wc,
                                                float* __restrict__ out, int N, int l) {
    int wid = (blockIdx.x * blockDim.x + threadIdx.x) >> 6;
    int lane = threadIdx.x & 63;
    if (wid >= N) return;
    int n = wid;
    float di = dinv[n];
    const float* xr = XW + (size_t)n * 96;
    int c0 = lane;                 // channels 0..63: [I(0..31) | T(0..31)]
    int c1 = 64 + (lane & 31);     // O channels (lanes>=32 redundant broadcast)
    float sw = di * di;            // self-loop: dinv*1*dinv
    float acc0 = sw * xr[c0];
    float acc1 = sw * xr[c1];
    int rs = row_start[n], re = row_start[n + 1];
    int2 ed;
    if (rs < re) ed = csr[rs];
    for (int e = rs; e < re; e++) {
        int2 cur = ed;
        if (e + 1 < re) ed = csr[e + 1];         // prefetch next edge
        int s = cur.x; float w = __int_as_float(cur.y);
        const float* sr = XW + (size_t)s * 96;
        acc0 += w * sr[c0];
        acc1 += w * sr[c1];
    }
    float accT = __shfl_xor(acc0, 32);
    if (lane < 32) {
        int c = lane;
        float bI = cb[((l * 8 + 0) * 32) + c] + cb[((l * 8 + 1) * 32) + c] + bgp[((l * 4 + 0) * 32) + c];
        float bT = cb[((l * 8 + 4) * 32) + c] + cb[((l * 8 + 5) * 32) + c] + bgp[((l * 4 + 2) * 32) + c];
        float bO = cb[((l * 8 + 6) * 32) + c] + cb[((l * 8 + 7) * 32) + c] + bgp[((l * 4 + 3) * 32) + c];
        float I = 1.f / (1.f + expf(-(acc0 + bI)));
        float T = tanhf(accT + bT);
        float C = I * T;                          // C_old = 0 -> F-gate dead
        float w2 = wc[((l * 3 + 2) * 32) + c];
        float O = 1.f / (1.f + expf(-(acc1 + w2 * C + bO)));
        out[(size_t)n * 32 + c] = O * tanhf(C);
    }
}

extern "C" void kernel_launch(void* const* d_in, const int* in_sizes, int n_in,
                              void* d_out, int out_size, void* d_ws, size_t ws_size,
                              hipStream_t stream) {
    const float* X  = (const float*)d_in[0];
    const int*   ei = (const int*)d_in[1];
    const float* ew = (const float*)d_in[2];
    const float* cw = (const float*)d_in[3];
    const float* cb = (const float*)d_in[4];
    const float* wc = (const float*)d_in[5];
    const float* bg = (const float*)d_in[6];
    int N = in_sizes[0] / 32;
    int E = in_sizes[2];
    int L = in_sizes[3] / (8 * 32 * 32);
    float* out = (float*)d_out;

    char* p = (char*)d_ws;
    auto alloc = [&](size_t bytes) -> char* {
        char* r = p; p += (bytes + 255) & ~(size_t)255; return r;
    };
    float* deg       = (float*)alloc((size_t)N * 4);        // becomes dinv in-place
    int*   cnt       = (int*)alloc((size_t)N * 4);          // becomes fill after scan
    int*   row_start = (int*)alloc((size_t)(N + 1) * 4);
    int*   tileSums  = (int*)alloc(1024 * 4);
    int2*  csr       = (int2*)alloc((size_t)E * 8);
    float* XW        = (float*)alloc((size_t)N * 96 * 4);

    int gN = (N + TPB - 1) / TPB, gE = (E + TPB - 1) / TPB;
    k_init<<<gN, TPB, 0, stream>>>(deg, cnt, N);
    k_count<<<gE, TPB, 0, stream>>>(ei, ew, deg, cnt, E);
    k_rsqrt<<<gN, TPB, 0, stream>>>(deg, N);
    int nTiles = (N + 1023) / 1024;
    k_scan1<<<nTiles, 256, 0, stream>>>(cnt, row_start, tileSums, N);
    k_scan2<<<1, 64, 0, stream>>>(tileSums, nTiles);
    k_scan3<<<gN, TPB, 0, stream>>>(row_start, tileSums, cnt, N, E);
    k_scatter<<<gE, TPB, 0, stream>>>(ei, ew, deg, row_start, cnt, csr, E);

    const float* xin = X;
    for (int l = 0; l < L; l++) {
        k_gemm<<<(N + 31) / 32, 256, 0, stream>>>(xin, cw, XW, N, l);
        k_gather<<<(N + 3) / 4, 256, 0, stream>>>(XW, row_start, csr, deg, cb, bg, wc, out, N, l);
        xin = out;                                // next layer reads previous output
    }
}

// Round 2
// 491.758 us; speedup vs baseline: 1.3926x; 1.3926x over previous
//
#include <hip/hip_runtime.h>
#include <math.h>

#define TPB 256

// ---------------- CSR build ----------------

__global__ void k_count(const int* __restrict__ ei, int* cnt, int E) {
    int e = blockIdx.x * blockDim.x + threadIdx.x;
    if (e < E) atomicAdd(&cnt[ei[E + e]], 1);     // dst in-degree (count only)
}

// exclusive scan of cnt[] -> row_start[], tile size 1024 (256 thr x 4)
__global__ void k_scan1(const int* __restrict__ cnt, int* __restrict__ excl,
                        int* __restrict__ tileSums, int n) {
    __shared__ int sh[256];
    int tid = threadIdx.x;
    int base = blockIdx.x * 1024;
    int idx0 = base + tid * 4;
    int v[4]; int tot = 0;
#pragma unroll
    for (int j = 0; j < 4; j++) { int i = idx0 + j; v[j] = (i < n) ? cnt[i] : 0; tot += v[j]; }
    sh[tid] = tot;
    __syncthreads();
    for (int off = 1; off < 256; off <<= 1) {
        int t = (tid >= off) ? sh[tid - off] : 0;
        __syncthreads();
        sh[tid] += t;
        __syncthreads();
    }
    int incl = sh[tid];
    if (tid == 255) tileSums[blockIdx.x] = incl;
    int run = incl - tot;
#pragma unroll
    for (int j = 0; j < 4; j++) { int i = idx0 + j; if (i < n) excl[i] = run; run += v[j]; }
}

__global__ void k_scan2(int* tileSums, int nTiles) {
    if (threadIdx.x == 0 && blockIdx.x == 0) {
        int acc = 0;
        for (int t = 0; t < nTiles; t++) { int v = tileSums[t]; tileSums[t] = acc; acc += v; }
    }
}

__global__ void k_scan3(int* __restrict__ excl, const int* __restrict__ tileSums,
                        int* __restrict__ fill, int n, int total) {
    int i = blockIdx.x * blockDim.x + threadIdx.x;
    if (i < n) { excl[i] += tileSums[i >> 10]; fill[i] = 0; }
    if (i == 0) excl[n] = total;
}

// store RAW edge weight; normalization folded into Y=dinv*x and dinv[dst] scale
__global__ void k_scatter(const int* __restrict__ ei, const float* __restrict__ ew,
                          const int* __restrict__ row_start,
                          int* fill, int2* __restrict__ csr, int E) {
    int e = blockIdx.x * blockDim.x + threadIdx.x;
    if (e >= E) return;
    int s = ei[e], d = ei[E + e];
    int r = atomicAdd(&fill[d], 1);
    int2 v; v.x = s; v.y = __float_as_int(ew[e]);
    csr[row_start[d] + r] = v;
}

// deg[d] = 1 + sum(row weights) from CSR (coalesced-ish, no atomics) -> dinv
__global__ void k_deg(const int2* __restrict__ csr, const int* __restrict__ row_start,
                      float* __restrict__ dinv, int N) {
    int n = blockIdx.x * blockDim.x + threadIdx.x;
    if (n >= N) return;
    int rs = row_start[n], re = row_start[n + 1];
    float s = 1.0f;                               // self-loop weight
    for (int e = rs; e < re; e++) s += __int_as_float(csr[e].y);
    dinv[n] = rsqrtf(s);                          // deg >= 1 always
}

// Y = dinv[n] * X[n,:]  (first-layer input prep)
__global__ void k_prep(const float* __restrict__ X, const float* __restrict__ dinv,
                       float* __restrict__ Y, int total) {
    int i = blockIdx.x * blockDim.x + threadIdx.x;
    if (i < total) Y[i] = X[i] * dinv[i >> 5];
}

// ---------------- per-layer compute ----------------

// AX[d,:] = dinv[d] * (Y[d,:] + sum_e w_e * Y[src_e,:])   (32 channels)
// one wave per node; two edges in flight (half-wave each)
__global__ __launch_bounds__(256) void k_gather(const float* __restrict__ Y,
                                                const int* __restrict__ row_start,
                                                const int2* __restrict__ csr,
                                                const float* __restrict__ dinv,
                                                float* __restrict__ AX, int N) {
    int wid = (blockIdx.x * blockDim.x + threadIdx.x) >> 6;
    if (wid >= N) return;
    int lane = threadIdx.x & 63;
    int h = lane >> 5, c = lane & 31;
    int rs = row_start[wid], re = row_start[wid + 1];
    float acc = (h == 0) ? Y[(size_t)wid * 32 + c] : 0.f;   // self-loop once
    int e = rs + h;
    int2 ed;
    if (e < re) ed = csr[e];
    for (; e < re; e += 2) {
        int2 cur = ed;
        if (e + 2 < re) ed = csr[e + 2];          // prefetch
        acc += __int_as_float(cur.y) * Y[(size_t)cur.x * 32 + c];
    }
    acc += __shfl_xor(acc, 32);
    if (lane < 32) AX[(size_t)wid * 32 + c] = dinv[wid] * acc;
}

// G = AX @ [W_I|W_T|W_O] + biases; fused gates; writes raw out (last layer)
// or Y_next = dinv * out (intermediate layers)
__global__ __launch_bounds__(256) void k_gates(const float* __restrict__ AX,
                                               const float* __restrict__ cw,
                                               const float* __restrict__ cb,
                                               const float* __restrict__ wc,
                                               const float* __restrict__ bg,
                                               const float* __restrict__ dinv,
                                               float* __restrict__ outRaw,
                                               float* __restrict__ outY,
                                               int N, int l, int isLast) {
    __shared__ float Ws[32][96];
    __shared__ float Xs[32][33];
    __shared__ float Gs[32][96];
    int tid = threadIdx.x;
    for (int i = tid; i < 3072; i += 256) {
        int k = i / 96, ccol = i - k * 96;
        int g = ccol >> 5, o = ccol & 31;
        int j = (g == 0) ? 0 : ((g == 1) ? 4 : 6); // I, T, O convs on x
        Ws[k][ccol] = cw[(((l * 8 + j) * 32) + k) * 32 + o];
    }
    int row0 = blockIdx.x * 32;
    for (int i = tid; i < 1024; i += 256) {
        int r = i >> 5, k = i & 31; int gr = row0 + r;
        Xs[r][k] = (gr < N) ? AX[(size_t)gr * 32 + k] : 0.f;
    }
    __syncthreads();
    {
        int r = tid >> 3, g8 = tid & 7;
        float acc[12];
#pragma unroll
        for (int j = 0; j < 12; j++) acc[j] = 0.f;
#pragma unroll
        for (int k = 0; k < 32; k++) {
            float xv = Xs[r][k];
#pragma unroll
            for (int j = 0; j < 12; j++) acc[j] += xv * Ws[k][g8 * 12 + j];
        }
#pragma unroll
        for (int j = 0; j < 12; j++) Gs[r][g8 * 12 + j] = acc[j];
    }
    __syncthreads();
    for (int i = tid; i < 1024; i += 256) {
        int r = i >> 5, c = i & 31;
        int gn = row0 + r;
        if (gn >= N) continue;
        float bI = cb[((l * 8 + 0) * 32) + c] + cb[((l * 8 + 1) * 32) + c] + bg[((l * 4 + 0) * 32) + c];
        float bT = cb[((l * 8 + 4) * 32) + c] + cb[((l * 8 + 5) * 32) + c] + bg[((l * 4 + 2) * 32) + c];
        float bO = cb[((l * 8 + 6) * 32) + c] + cb[((l * 8 + 7) * 32) + c] + bg[((l * 4 + 3) * 32) + c];
        float I = 1.f / (1.f + expf(-(Gs[r][c] + bI)));
        float T = tanhf(Gs[r][32 + c] + bT);
        float C = I * T;                          // C_old = 0, F-gate dead
        float O = 1.f / (1.f + expf(-(Gs[r][64 + c] + wc[((l * 3 + 2) * 32) + c] * C + bO)));
        float val = O * tanhf(C);
        if (isLast) outRaw[(size_t)gn * 32 + c] = val;
        else        outY[(size_t)gn * 32 + c] = dinv[gn] * val;
    }
}

extern "C" void kernel_launch(void* const* d_in, const int* in_sizes, int n_in,
                              void* d_out, int out_size, void* d_ws, size_t ws_size,
                              hipStream_t stream) {
    const float* X  = (const float*)d_in[0];
    const int*   ei = (const int*)d_in[1];
    const float* ew = (const float*)d_in[2];
    const float* cw = (const float*)d_in[3];
    const float* cb = (const float*)d_in[4];
    const float* wc = (const float*)d_in[5];
    const float* bg = (const float*)d_in[6];
    int N = in_sizes[0] / 32;
    int E = in_sizes[2];
    int L = in_sizes[3] / (8 * 32 * 32);
    float* out = (float*)d_out;

    char* p = (char*)d_ws;
    auto alloc = [&](size_t bytes) -> char* {
        char* r = p; p += (bytes + 255) & ~(size_t)255; return r;
    };
    int*   cnt       = (int*)alloc((size_t)N * 4);          // becomes fill after scan
    int*   row_start = (int*)alloc((size_t)(N + 1) * 4);
    int*   tileSums  = (int*)alloc(1024 * 4);
    float* dinv      = (float*)alloc((size_t)N * 4);
    int2*  csr       = (int2*)alloc((size_t)E * 8);
    float* Y         = (float*)alloc((size_t)N * 32 * 4);
    float* AX        = (float*)alloc((size_t)N * 32 * 4);

    int gN = (N + TPB - 1) / TPB, gE = (E + TPB - 1) / TPB;
    hipMemsetAsync(cnt, 0, (size_t)N * 4, stream);
    k_count<<<gE, TPB, 0, stream>>>(ei, cnt, E);
    int nTiles = (N + 1023) / 1024;
    k_scan1<<<nTiles, 256, 0, stream>>>(cnt, row_start, tileSums, N);
    k_scan2<<<1, 64, 0, stream>>>(tileSums, nTiles);
    k_scan3<<<gN, TPB, 0, stream>>>(row_start, tileSums, cnt, N, E);
    k_scatter<<<gE, TPB, 0, stream>>>(ei, ew, row_start, cnt, csr, E);
    k_deg<<<gN, TPB, 0, stream>>>(csr, row_start, dinv, N);
    k_prep<<<(N * 32 + TPB - 1) / TPB, TPB, 0, stream>>>(X, dinv, Y, N * 32);

    for (int l = 0; l < L; l++) {
        k_gather<<<(N + 3) / 4, 256, 0, stream>>>(Y, row_start, csr, dinv, AX, N);
        k_gates<<<(N + 31) / 32, 256, 0, stream>>>(AX, cw, cb, wc, bg, dinv,
                                                   out, Y, N, l, l == L - 1);
    }
}

// Round 3
// 372.155 us; speedup vs baseline: 1.8402x; 1.3214x over previous
//
#include <hip/hip_runtime.h>
#include <math.h>

#define TPB 256
#define NBMAX 2048          // buckets of 256 nodes -> supports N <= 524288

// ---------------- bucketed CSR build ----------------

// bucket histogram (bucket = dst >> 8), LDS-aggregated
__global__ __launch_bounds__(256) void k_bhist(const int* __restrict__ ei,
                                               int* __restrict__ bhist, int E, int NB) {
    __shared__ int h[NBMAX];
    for (int i = threadIdx.x; i < NB; i += 256) h[i] = 0;
    __syncthreads();
    int stride = gridDim.x * 256;
    for (int e = blockIdx.x * 256 + threadIdx.x; e < E; e += stride)
        atomicAdd(&h[ei[E + e] >> 8], 1);
    __syncthreads();
    for (int i = threadIdx.x; i < NB; i += 256) if (h[i]) atomicAdd(&bhist[i], h[i]);
}

// exclusive scan of bucket counts; bfill = bbase; sentinel entries
__global__ __launch_bounds__(256) void k_bscan(const int* __restrict__ bhist,
                                               int* __restrict__ bbase, int* __restrict__ bfill,
                                               int* __restrict__ row_start,
                                               int NB, int N, int E) {
    __shared__ int tsum[256];
    int tid = threadIdx.x;
    int per = (NB + 255) / 256;           // <= 8
    int loc[8]; int tot = 0;
    int base = tid * per;
#pragma unroll
    for (int j = 0; j < 8; j++) {
        int i = base + j;
        int v = (j < per && i < NB) ? bhist[i] : 0;
        loc[j] = v; tot += v;
    }
    tsum[tid] = tot;
    __syncthreads();
    for (int off = 1; off < 256; off <<= 1) {
        int t = (tid >= off) ? tsum[tid - off] : 0;
        __syncthreads();
        tsum[tid] += t;
        __syncthreads();
    }
    int run = tsum[tid] - tot;
#pragma unroll
    for (int j = 0; j < 8; j++) {
        int i = base + j;
        if (j < per && i < NB) { bbase[i] = run; bfill[i] = run; run += loc[j]; }
    }
    if (tid == 0) { bbase[NB] = E; row_start[N] = E; }
}

// bin edges into bucket-contiguous ebuf: {src | dlow<<24, weight}
__global__ __launch_bounds__(256) void k_bin(const int* __restrict__ ei,
                                             const float* __restrict__ ew,
                                             int* bfill, int2* __restrict__ ebuf,
                                             int E, int NB) {
    __shared__ int h[NBMAX];
    __shared__ int gb[NBMAX];
    const int EPT = 16;
    int tid = threadIdx.x;
    int base = blockIdx.x * 256 * EPT;
    for (int i = tid; i < NB; i += 256) h[i] = 0;
    __syncthreads();
    int src[EPT]; float w[EPT]; int bkt[EPT]; int lrank[EPT];
#pragma unroll
    for (int j = 0; j < EPT; j++) {
        int e = base + j * 256 + tid;              // coalesced
        if (e < E) {
            src[j] = ei[e]; int d = ei[E + e]; w[j] = ew[e];
            int b = d >> 8;
            bkt[j] = b | ((d & 255) << 16);
            lrank[j] = atomicAdd(&h[b], 1);
        } else bkt[j] = -1;
    }
    __syncthreads();
    for (int i = tid; i < NB; i += 256) gb[i] = h[i] ? atomicAdd(&bfill[i], h[i]) : 0;
    __syncthreads();
#pragma unroll
    for (int j = 0; j < EPT; j++) {
        if (bkt[j] >= 0) {
            int b = bkt[j] & 0xFFFF, dlow = (bkt[j] >> 16) & 0xFF;
            int2 v; v.x = src[j] | (dlow << 24); v.y = __float_as_int(w[j]);
            ebuf[gb[b] + lrank[j]] = v;
        }
    }
}

// per bucket (256 nodes): local counts + weight sums -> row_start, dinv, final CSR
__global__ __launch_bounds__(256) void k_bucket(const int2* __restrict__ ebuf,
                                                const int* __restrict__ bbase,
                                                int2* __restrict__ csr,
                                                int* __restrict__ row_start,
                                                float* __restrict__ dinv,
                                                int N, int E) {
    __shared__ int lcnt[256];
    __shared__ float wsum[256];
    __shared__ int lstart[256];
    __shared__ int sc[256];
    int b = blockIdx.x, tid = threadIdx.x;
    int beg = bbase[b], end = bbase[b + 1];
    lcnt[tid] = 0; wsum[tid] = 0.f;
    __syncthreads();
    for (int i = beg + tid; i < end; i += 256) {
        int2 v = ebuf[i];
        int dlow = ((unsigned)v.x) >> 24;
        atomicAdd(&lcnt[dlow], 1);
        atomicAdd(&wsum[dlow], __int_as_float(v.y));
    }
    __syncthreads();
    int myc = lcnt[tid];
    sc[tid] = myc;
    __syncthreads();
    for (int off = 1; off < 256; off <<= 1) {
        int t = (tid >= off) ? sc[tid - off] : 0;
        __syncthreads();
        sc[tid] += t;
        __syncthreads();
    }
    lstart[tid] = sc[tid] - myc;
    int node = (b << 8) + tid;
    if (node < N) {
        row_start[node] = beg + sc[tid] - myc;
        dinv[node] = rsqrtf(1.0f + wsum[tid]);    // self-loop weight 1; deg >= 1
    }
    lcnt[tid] = 0;
    __syncthreads();
    for (int i = beg + tid; i < end; i += 256) {
        int2 v = ebuf[i];
        int dlow = ((unsigned)v.x) >> 24;
        int pos = lstart[dlow] + atomicAdd(&lcnt[dlow], 1);
        int2 o; o.x = v.x & 0x00FFFFFF; o.y = v.y;
        csr[beg + pos] = o;                        // confined to 32KB bucket segment
    }
}

// Y = dinv[n] * X[n,:]  (first-layer input prep)
__global__ void k_prep(const float* __restrict__ X, const float* __restrict__ dinv,
                       float* __restrict__ Y, int total) {
    int i = blockIdx.x * blockDim.x + threadIdx.x;
    if (i < total) Y[i] = X[i] * dinv[i >> 5];
}

// ---------------- per-layer compute ----------------

// AX[d,:] = dinv[d] * (Y[d,:] + sum_e w_e * Y[src_e,:])   (32 channels)
__global__ __launch_bounds__(256) void k_gather(const float* __restrict__ Y,
                                                const int* __restrict__ row_start,
                                                const int2* __restrict__ csr,
                                                const float* __restrict__ dinv,
                                                float* __restrict__ AX, int N) {
    int wid = (blockIdx.x * blockDim.x + threadIdx.x) >> 6;
    if (wid >= N) return;
    int lane = threadIdx.x & 63;
    int h = lane >> 5, c = lane & 31;
    int rs = row_start[wid], re = row_start[wid + 1];
    float acc = (h == 0) ? Y[(size_t)wid * 32 + c] : 0.f;   // self-loop once
    int e = rs + h;
    int2 ed;
    if (e < re) ed = csr[e];
    for (; e < re; e += 2) {
        int2 cur = ed;
        if (e + 2 < re) ed = csr[e + 2];          // prefetch
        acc += __int_as_float(cur.y) * Y[(size_t)cur.x * 32 + c];
    }
    acc += __shfl_xor(acc, 32);
    if (lane < 32) AX[(size_t)wid * 32 + c] = dinv[wid] * acc;
}

// G = AX @ [W_I|W_T|W_O] + biases; fused gates
__global__ __launch_bounds__(256) void k_gates(const float* __restrict__ AX,
                                               const float* __restrict__ cw,
                                               const float* __restrict__ cb,
                                               const float* __restrict__ wc,
                                               const float* __restrict__ bg,
                                               const float* __restrict__ dinv,
                                               float* __restrict__ outRaw,
                                               float* __restrict__ outY,
                                               int N, int l, int isLast) {
    __shared__ float Ws[32][96];
    __shared__ float Xs[32][33];
    __shared__ float Gs[32][96];
    int tid = threadIdx.x;
    for (int i = tid; i < 3072; i += 256) {
        int k = i / 96, ccol = i - k * 96;
        int g = ccol >> 5, o = ccol & 31;
        int j = (g == 0) ? 0 : ((g == 1) ? 4 : 6); // I, T, O convs on x
        Ws[k][ccol] = cw[(((l * 8 + j) * 32) + k) * 32 + o];
    }
    int row0 = blockIdx.x * 32;
    for (int i = tid; i < 1024; i += 256) {
        int r = i >> 5, k = i & 31; int gr = row0 + r;
        Xs[r][k] = (gr < N) ? AX[(size_t)gr * 32 + k] : 0.f;
    }
    __syncthreads();
    {
        int r = tid >> 3, g8 = tid & 7;
        float acc[12];
#pragma unroll
        for (int j = 0; j < 12; j++) acc[j] = 0.f;
#pragma unroll
        for (int k = 0; k < 32; k++) {
            float xv = Xs[r][k];
#pragma unroll
            for (int j = 0; j < 12; j++) acc[j] += xv * Ws[k][g8 * 12 + j];
        }
#pragma unroll
        for (int j = 0; j < 12; j++) Gs[r][g8 * 12 + j] = acc[j];
    }
    __syncthreads();
    for (int i = tid; i < 1024; i += 256) {
        int r = i >> 5, c = i & 31;
        int gn = row0 + r;
        if (gn >= N) continue;
        float bI = cb[((l * 8 + 0) * 32) + c] + cb[((l * 8 + 1) * 32) + c] + bg[((l * 4 + 0) * 32) + c];
        float bT = cb[((l * 8 + 4) * 32) + c] + cb[((l * 8 + 5) * 32) + c] + bg[((l * 4 + 2) * 32) + c];
        float bO = cb[((l * 8 + 6) * 32) + c] + cb[((l * 8 + 7) * 32) + c] + bg[((l * 4 + 3) * 32) + c];
        float I = 1.f / (1.f + expf(-(Gs[r][c] + bI)));
        float T = tanhf(Gs[r][32 + c] + bT);
        float C = I * T;                          // C_old = 0, F-gate dead
        float O = 1.f / (1.f + expf(-(Gs[r][64 + c] + wc[((l * 3 + 2) * 32) + c] * C + bO)));
        float val = O * tanhf(C);
        if (isLast) outRaw[(size_t)gn * 32 + c] = val;
        else        outY[(size_t)gn * 32 + c] = dinv[gn] * val;
    }
}

extern "C" void kernel_launch(void* const* d_in, const int* in_sizes, int n_in,
                              void* d_out, int out_size, void* d_ws, size_t ws_size,
                              hipStream_t stream) {
    const float* X  = (const float*)d_in[0];
    const int*   ei = (const int*)d_in[1];
    const float* ew = (const float*)d_in[2];
    const float* cw = (const float*)d_in[3];
    const float* cb = (const float*)d_in[4];
    const float* wc = (const float*)d_in[5];
    const float* bg = (const float*)d_in[6];
    int N = in_sizes[0] / 32;
    int E = in_sizes[2];
    int L = in_sizes[3] / (8 * 32 * 32);
    float* out = (float*)d_out;
    int NB = (N + 255) >> 8;

    char* p = (char*)d_ws;
    auto alloc = [&](size_t bytes) -> char* {
        char* r = p; p += (bytes + 255) & ~(size_t)255; return r;
    };
    int*   bhist     = (int*)alloc((size_t)NB * 4);
    int*   bbase     = (int*)alloc((size_t)(NB + 1) * 4);
    int*   bfill     = (int*)alloc((size_t)NB * 4);
    int*   row_start = (int*)alloc((size_t)(N + 1) * 4);
    float* dinv      = (float*)alloc((size_t)N * 4);
    int2*  ebuf      = (int2*)alloc((size_t)E * 8);
    int2*  csr       = (int2*)alloc((size_t)E * 8);
    float* Y         = (float*)alloc((size_t)N * 32 * 4);
    float* AX        = (float*)alloc((size_t)N * 32 * 4);

    hipMemsetAsync(bhist, 0, (size_t)NB * 4, stream);
    k_bhist<<<512, 256, 0, stream>>>(ei, bhist, E, NB);
    k_bscan<<<1, 256, 0, stream>>>(bhist, bbase, bfill, row_start, NB, N, E);
    int nBin = (E + 4095) / 4096;
    k_bin<<<nBin, 256, 0, stream>>>(ei, ew, bfill, ebuf, E, NB);
    k_bucket<<<NB, 256, 0, stream>>>(ebuf, bbase, csr, row_start, dinv, N, E);
    k_prep<<<(N * 32 + TPB - 1) / TPB, TPB, 0, stream>>>(X, dinv, Y, N * 32);

    for (int l = 0; l < L; l++) {
        k_gather<<<(N + 3) / 4, 256, 0, stream>>>(Y, row_start, csr, dinv, AX, N);
        k_gates<<<(N + 31) / 32, 256, 0, stream>>>(AX, cw, cb, wc, bg, dinv,
                                                   out, Y, N, l, l == L - 1);
    }
}